// Round 8
// baseline (79.382 us; speedup 1.0000x reference)
//
#include <hip/hip_runtime.h>
#include <hip/hip_bf16.h>

#define DD 128
#define NEGS 0.01f

typedef float  f32x4 __attribute__((ext_vector_type(4)));
typedef __bf16 bf16x8 __attribute__((ext_vector_type(8)));
typedef unsigned short us8 __attribute__((ext_vector_type(8)));

__device__ __forceinline__ unsigned short f2bf(float f) {
    unsigned int u = __builtin_bit_cast(unsigned int, f);
    u += 0x7FFFu + ((u >> 16) & 1u);          // RNE (no NaN inputs here)
    return (unsigned short)(u >> 16);
}
__device__ __forceinline__ float bflo(unsigned int u) {
    return __builtin_bit_cast(float, u << 16);
}
__device__ __forceinline__ float bfhi(unsigned int u) {
    return __builtin_bit_cast(float, u & 0xFFFF0000u);
}

// -------- aux: blocks [0,64): W fp32->bf16 ; blocks [64,..): segment starts --
__global__ __launch_bounds__(256)
void k_aux(const float* __restrict__ W, unsigned short* __restrict__ W16,
           const int* __restrict__ dst, int E, int N, int* __restrict__ start)
{
    int b = blockIdx.x;
    if (b < 64) {
        int i = b * 256 + threadIdx.x;
        W16[i] = f2bf(W[i]);
    } else {
        int n = (b - 64) * 256 + threadIdx.x;
        if (n > N) return;
        int lo = 0, hi = E;
        while (lo < hi) {
            int mid = (lo + hi) >> 1;
            if (dst[mid] < n) lo = mid + 1; else hi = mid;
        }
        start[n] = lo;
    }
}

// ---------- fused GEMM + logits: z16 = bf16(h @ W^T), ll/lr = z @ a --------
// One wave computes 16 rows of z (1 row-tile x 8 col-tiles, K=128).
// C/D mapping: col = lane&15, row = (lane>>4)*4 + reg   [m89 verified]
__global__ __launch_bounds__(256)
void k_gemm_mfma(const float* __restrict__ h, const unsigned short* __restrict__ W16,
                 const float* __restrict__ attn,
                 unsigned short* __restrict__ z16,
                 float* __restrict__ ll, float* __restrict__ lr, int N)
{
    const int lane = threadIdx.x & 63;
    const int gw   = (blockIdx.x * 256 + threadIdx.x) >> 6;
    const int i0   = gw * 16;
    if (i0 >= N) return;
    const int hl = lane & 15;
    const int g  = lane >> 4;
    const int ko = g * 8;

    int r0 = i0 + hl; if (r0 > N - 1) r0 = N - 1;   // clamp loads; stores guarded

    f32x4 acc[8];
#pragma unroll
    for (int jt = 0; jt < 8; ++jt) acc[jt] = f32x4{0.f, 0.f, 0.f, 0.f};

#pragma unroll
    for (int kk = 0; kk < DD; kk += 32) {
        const float* pa = h + (size_t)r0 * DD + kk + ko;
        float4 va = *(const float4*)pa, vb = *(const float4*)(pa + 4);
        us8 ua = { f2bf(va.x), f2bf(va.y), f2bf(va.z), f2bf(va.w),
                   f2bf(vb.x), f2bf(vb.y), f2bf(vb.z), f2bf(vb.w) };
        bf16x8 a = __builtin_bit_cast(bf16x8, ua);
#pragma unroll
        for (int jt = 0; jt < 8; ++jt) {
            us8 ub = *(const us8*)(W16 + (size_t)(jt * 16 + hl) * DD + kk + ko);
            bf16x8 b = __builtin_bit_cast(bf16x8, ub);
            acc[jt] = __builtin_amdgcn_mfma_f32_16x16x32_bf16(a, b, acc[jt], 0, 0, 0);
        }
    }

    float aLc[8], aRc[8];
#pragma unroll
    for (int jt = 0; jt < 8; ++jt) {
        aLc[jt] = attn[jt * 16 + hl];
        aRc[jt] = attn[DD + jt * 16 + hl];
    }
#pragma unroll
    for (int reg = 0; reg < 4; ++reg) {
        const int row = i0 + g * 4 + reg;
        float pl = 0.f, pr = 0.f;
#pragma unroll
        for (int jt = 0; jt < 8; ++jt) {
            float v = acc[jt][reg];
            pl = fmaf(v, aLc[jt], pl);
            pr = fmaf(v, aRc[jt], pr);
        }
#pragma unroll
        for (int o = 8; o >= 1; o >>= 1) {
            pl += __shfl_xor(pl, o);
            pr += __shfl_xor(pr, o);
        }
        if (row < N) {
            if (hl == 0) { ll[row] = pl; lr[row] = pr; }
            unsigned short* zr = z16 + (size_t)row * DD;
#pragma unroll
            for (int jt = 0; jt < 8; ++jt)
                zr[jt * 16 + hl] = f2bf(acc[jt][reg]);
        }
    }
}

// ---------------- fused output, 32-lane rows: 4 edges/iter ----------------
// wave = node. Quarter q stages edge base+q's metadata (src, ll-gather, w);
// shuffles broadcast; each half-wave (32 lanes x 8B = 256B) reads one full
// z row per instr -> 2 z-load instrs cover 4 edges. Requests/edge ~3.25 vs
// 5.25 before. No max-subtraction (logits O(10), softmax shift-invariant).
__global__ __launch_bounds__(256)
void k_out(const unsigned short* __restrict__ z16, const int* __restrict__ src,
           const float* __restrict__ ll, const float* __restrict__ lr,
           const int* __restrict__ start, float* __restrict__ out, int N)
{
    int wid  = (blockIdx.x * 256 + threadIdx.x) >> 6;
    int lane = threadIdx.x & 63;
    if (wid >= N) return;
    const int s0 = start[wid], s1 = start[wid + 1];
    const int q   = lane >> 4;      // staging quarter: edge base+q
    const int l32 = lane & 31;      // bf16 cols 4*l32 .. 4*l32+3
    const float lrn = lr[wid];
    const int last = s1 - 1;
    const bool hi = (lane >= 32);

    float a0 = 0.f, a1 = 0.f, a2 = 0.f, a3 = 0.f, ssum = 0.f;

    for (int base = s0; base < s1; base += 4) {
        int t  = base + q;
        int tc = (t <= last) ? t : last;
        int sj = __builtin_nontemporal_load(src + tc);
        float v = ll[sj] + lrn;  v = (v >= 0.f) ? v : NEGS * v;
        float w = __expf(v); if (t > last) w = 0.f;
        ssum += w;                       // per-lane: only its quarter's edges

        // broadcast staged metadata; halves process edges (0,1) then (2,3)
        int   sjA = __shfl(sj, 0),  sjB = __shfl(sj, 16);
        int   sjC = __shfl(sj, 32), sjD = __shfl(sj, 48);
        float wA  = __shfl(w, 0),   wB  = __shfl(w, 16);
        float wC  = __shfl(w, 32),  wD  = __shfl(w, 48);
        int   rowX = hi ? sjB : sjA;   float wX = hi ? wB : wA;
        int   rowY = hi ? sjD : sjC;   float wY = hi ? wD : wC;

        uint2 zx = *(const uint2*)(z16 + (size_t)rowX * DD + l32 * 4);
        uint2 zy = *(const uint2*)(z16 + (size_t)rowY * DD + l32 * 4);
        a0 = fmaf(wX, bflo(zx.x), a0);  a1 = fmaf(wX, bfhi(zx.x), a1);
        a2 = fmaf(wX, bflo(zx.y), a2);  a3 = fmaf(wX, bfhi(zx.y), a3);
        a0 = fmaf(wY, bflo(zy.x), a0);  a1 = fmaf(wY, bfhi(zy.x), a1);
        a2 = fmaf(wY, bflo(zy.y), a2);  a3 = fmaf(wY, bfhi(zy.y), a3);
    }
    // cross-half: lanes l, l^32 hold the same 4 cols
    a0 += __shfl_xor(a0, 32);  a1 += __shfl_xor(a1, 32);
    a2 += __shfl_xor(a2, 32);  a3 += __shfl_xor(a3, 32);
    // ssum: sum the 4 quarters (lanes within a quarter are identical)
    ssum += __shfl_xor(ssum, 16);
    ssum += __shfl_xor(ssum, 32);
    float inv = (s1 > s0) ? 1.0f / ssum : 0.f;   // empty segment -> zeros

    if (!hi) {
        f32x4 o = {a0 * inv, a1 * inv, a2 * inv, a3 * inv};
        __builtin_nontemporal_store(o, (f32x4*)(out + (size_t)wid * DD + l32 * 4));
    }
}

extern "C" void kernel_launch(void* const* d_in, const int* in_sizes, int n_in,
                              void* d_out, int out_size, void* d_ws, size_t ws_size,
                              hipStream_t stream) {
    const float* h    = (const float*)d_in[0];
    const int*   src  = (const int*)d_in[1];
    const int*   dst  = (const int*)d_in[2];
    const float* W    = (const float*)d_in[3];
    const float* attn = (const float*)d_in[4];
    const int N = in_sizes[0] / DD;
    const int E = in_sizes[1];
    float* out = (float*)d_out;

    // workspace layout
    unsigned short* z16 = (unsigned short*)d_ws;          // N*128 bf16 (12.8 MB)
    float* ll  = (float*)(z16 + (size_t)N * DD);          // N
    float* lr  = ll + N;                                  // N
    int* start = (int*)(lr + N);                          // N+1
    unsigned short* W16 = (unsigned short*)(start + N + 1); // 16384

    k_aux<<<64 + (N + 1 + 255) / 256, 256, 0, stream>>>(W, W16, dst, E, N, start);
    k_gemm_mfma<<<(N + 63) / 64, 256, 0, stream>>>(h, W16, attn, z16, ll, lr, N);
    k_out<<<(N + 3) / 4, 256, 0, stream>>>(z16, src, ll, lr, start, out, N);
}

// Round 9
// 55.537 us; speedup vs baseline: 1.4294x; 1.4294x over previous
//
#include <hip/hip_runtime.h>
#include <hip/hip_bf16.h>

#define DD 128
#define NEGS 0.01f

typedef float  f32x4 __attribute__((ext_vector_type(4)));
typedef __bf16 bf16x8 __attribute__((ext_vector_type(8)));
typedef unsigned short us8 __attribute__((ext_vector_type(8)));

__device__ __forceinline__ unsigned short f2bf(float f) {
    unsigned int u = __builtin_bit_cast(unsigned int, f);
    u += 0x7FFFu + ((u >> 16) & 1u);          // RNE (no NaN inputs here)
    return (unsigned short)(u >> 16);
}
__device__ __forceinline__ float bflo(unsigned int u) {
    return __builtin_bit_cast(float, u << 16);
}
__device__ __forceinline__ float bfhi(unsigned int u) {
    return __builtin_bit_cast(float, u & 0xFFFF0000u);
}

// ---------- fused GEMM + logits + segment-starts (one kernel) --------------
// Blocks [0,NB): GEMM. 256 thr = 4 waves x 32 rows = 128 rows/block.
// h and W staged in LDS as bf16, rows of 16 chunks x 16B, slot-swizzled
// slot = c ^ (r&15) so frag ds_read_b128 (16 lanes, 16 rows, same chunk)
// spreads across slots -> ~2-way bank conflict (free, m136).
// Blocks [NB, NB+SB): start[n] = lower_bound(dst, n).
__global__ __launch_bounds__(256)
void k_gemm(const float* __restrict__ h, const float* __restrict__ W,
            const float* __restrict__ attn, const int* __restrict__ dst,
            int E, int N, int NB,
            unsigned short* __restrict__ z16,
            float* __restrict__ ll, float* __restrict__ lr,
            int* __restrict__ start)
{
    if (blockIdx.x >= NB) {               // ---- segment starts part ----
        int n = (blockIdx.x - NB) * 256 + threadIdx.x;
        if (n > N) return;
        int lo = 0, hi = E;
        while (lo < hi) {
            int mid = (lo + hi) >> 1;
            if (dst[mid] < n) lo = mid + 1; else hi = mid;
        }
        start[n] = lo;
        return;
    }

    __shared__ unsigned short hs[128 * DD];   // 32 KB, swizzled bf16
    __shared__ unsigned short ws[DD * DD];    // 32 KB, swizzled bf16
    const int tid  = threadIdx.x;
    const int row0 = blockIdx.x * 128;

    // stage W (fp32 -> bf16, swizzled). thread t: row p+(t>>4), chunk t&15.
    {
        const int r = tid >> 4, c = tid & 15;
#pragma unroll
        for (int p = 0; p < DD; p += 16) {
            const int rr = p + r;
            const float* pw = W + (size_t)rr * DD + c * 8;
            float4 a = *(const float4*)pw, b = *(const float4*)(pw + 4);
            us8 v = { f2bf(a.x), f2bf(a.y), f2bf(a.z), f2bf(a.w),
                      f2bf(b.x), f2bf(b.y), f2bf(b.z), f2bf(b.w) };
            *(us8*)(ws + rr * DD + ((c ^ (rr & 15)) * 8)) = v;
        }
    }
    // stage h rows [row0, row0+128) (clamped), same layout
    {
        const int r = tid >> 4, c = tid & 15;
#pragma unroll
        for (int p = 0; p < 128; p += 16) {
            const int rr = p + r;
            int gr = row0 + rr; if (gr > N - 1) gr = N - 1;
            const float* ph = h + (size_t)gr * DD + c * 8;
            float4 a = *(const float4*)ph, b = *(const float4*)(ph + 4);
            us8 v = { f2bf(a.x), f2bf(a.y), f2bf(a.z), f2bf(a.w),
                      f2bf(b.x), f2bf(b.y), f2bf(b.z), f2bf(b.w) };
            *(us8*)(hs + rr * DD + ((c ^ (rr & 15)) * 8)) = v;
        }
    }
    __syncthreads();

    // compute: wave w does 32 rows (2 row-tiles x 8 col-tiles), K=128
    const int w    = tid >> 6;
    const int lane = tid & 63;
    const int hl   = lane & 15;
    const int g    = lane >> 4;

    f32x4 acc[2][8];
#pragma unroll
    for (int rt = 0; rt < 2; ++rt)
#pragma unroll
        for (int jt = 0; jt < 8; ++jt) acc[rt][jt] = f32x4{0.f, 0.f, 0.f, 0.f};

#pragma unroll
    for (int kk = 0; kk < DD; kk += 32) {
        const int cb = (kk >> 3) + g;         // 16B chunk index of this k-group
        const int ra0 = w * 32 + hl;
        const int ra1 = ra0 + 16;
        bf16x8 a0 = *(const bf16x8*)(hs + ra0 * DD + ((cb ^ (ra0 & 15)) * 8));
        bf16x8 a1 = *(const bf16x8*)(hs + ra1 * DD + ((cb ^ (ra1 & 15)) * 8));
#pragma unroll
        for (int jt = 0; jt < 8; ++jt) {
            const int rb = jt * 16 + hl;
            bf16x8 b = *(const bf16x8*)(ws + rb * DD + ((cb ^ (rb & 15)) * 8));
            acc[0][jt] = __builtin_amdgcn_mfma_f32_16x16x32_bf16(a0, b, acc[0][jt], 0, 0, 0);
            acc[1][jt] = __builtin_amdgcn_mfma_f32_16x16x32_bf16(a1, b, acc[1][jt], 0, 0, 0);
        }
    }

    // epilogue: store z16 + fused logits (C/D: col=lane&15, row=(lane>>4)*4+reg)
    float aLc[8], aRc[8];
#pragma unroll
    for (int jt = 0; jt < 8; ++jt) {
        aLc[jt] = attn[jt * 16 + hl];
        aRc[jt] = attn[DD + jt * 16 + hl];
    }
#pragma unroll
    for (int rt = 0; rt < 2; ++rt) {
#pragma unroll
        for (int reg = 0; reg < 4; ++reg) {
            const int row = row0 + w * 32 + rt * 16 + g * 4 + reg;
            float pl = 0.f, pr = 0.f;
#pragma unroll
            for (int jt = 0; jt < 8; ++jt) {
                float v = acc[rt][jt][reg];
                pl = fmaf(v, aLc[jt], pl);
                pr = fmaf(v, aRc[jt], pr);
            }
#pragma unroll
            for (int o = 8; o >= 1; o >>= 1) {
                pl += __shfl_xor(pl, o);
                pr += __shfl_xor(pr, o);
            }
            if (row < N) {
                if (hl == 0) { ll[row] = pl; lr[row] = pr; }
                unsigned short* zr = z16 + (size_t)row * DD;
#pragma unroll
                for (int jt = 0; jt < 8; ++jt)
                    zr[jt * 16 + hl] = f2bf(acc[rt][jt][reg]);
            }
        }
    }
}

// ---------------- fused output: w on-the-fly + weighted gather ------------
// (round-7 version — request-minimal shape: quarter-wave x uint4 = 8 edges/iter)
__global__ __launch_bounds__(256)
void k_out(const unsigned short* __restrict__ z16, const int* __restrict__ src,
           const float* __restrict__ ll, const float* __restrict__ lr,
           const int* __restrict__ start, float* __restrict__ out, int N)
{
    int wid  = (blockIdx.x * 256 + threadIdx.x) >> 6;
    int lane = threadIdx.x & 63;
    if (wid >= N) return;
    const int s0 = start[wid], s1 = start[wid + 1];
    const int q = lane >> 4;      // quarter 0..3
    const int c = lane & 15;      // col block: cols 8c .. 8c+7
    const float lrn = lr[wid];

    float acc[8];
#pragma unroll
    for (int k = 0; k < 8; ++k) acc[k] = 0.f;
    float ssum = 0.f;
    const int last = s1 - 1;

    for (int base = s0; base < s1; base += 8) {
        int t0 = base + q;
        int t1 = t0 + 4;
        int tc0 = (t0 <= last) ? t0 : last;
        int tc1 = (t1 <= last) ? t1 : last;
        int sj0 = __builtin_nontemporal_load(src + tc0);
        int sj1 = __builtin_nontemporal_load(src + tc1);
        float v0 = ll[sj0] + lrn;  v0 = (v0 >= 0.f) ? v0 : NEGS * v0;
        float v1 = ll[sj1] + lrn;  v1 = (v1 >= 0.f) ? v1 : NEGS * v1;
        float w0 = __expf(v0); if (t0 > last) w0 = 0.f;
        float w1 = __expf(v1); if (t1 > last) w1 = 0.f;
        uint4 z0 = *(const uint4*)(z16 + (size_t)sj0 * DD + c * 8);
        uint4 z1 = *(const uint4*)(z16 + (size_t)sj1 * DD + c * 8);
        ssum += w0 + w1;
        acc[0] = fmaf(w0, bflo(z0.x), fmaf(w1, bflo(z1.x), acc[0]));
        acc[1] = fmaf(w0, bfhi(z0.x), fmaf(w1, bfhi(z1.x), acc[1]));
        acc[2] = fmaf(w0, bflo(z0.y), fmaf(w1, bflo(z1.y), acc[2]));
        acc[3] = fmaf(w0, bfhi(z0.y), fmaf(w1, bfhi(z1.y), acc[3]));
        acc[4] = fmaf(w0, bflo(z0.z), fmaf(w1, bflo(z1.z), acc[4]));
        acc[5] = fmaf(w0, bfhi(z0.z), fmaf(w1, bfhi(z1.z), acc[5]));
        acc[6] = fmaf(w0, bflo(z0.w), fmaf(w1, bflo(z1.w), acc[6]));
        acc[7] = fmaf(w0, bfhi(z0.w), fmaf(w1, bfhi(z1.w), acc[7]));
    }
#pragma unroll
    for (int k = 0; k < 8; ++k) {
        acc[k] += __shfl_xor(acc[k], 16);
        acc[k] += __shfl_xor(acc[k], 32);
    }
    ssum += __shfl_xor(ssum, 16);
    ssum += __shfl_xor(ssum, 32);
    float inv = (s1 > s0) ? 1.0f / ssum : 0.f;   // empty segment -> zeros

    float* orow = out + (size_t)wid * DD + c * 8;
    if (q == 0) {
        f32x4 o = {acc[0]*inv, acc[1]*inv, acc[2]*inv, acc[3]*inv};
        __builtin_nontemporal_store(o, (f32x4*)orow);
    } else if (q == 1) {
        f32x4 o = {acc[4]*inv, acc[5]*inv, acc[6]*inv, acc[7]*inv};
        __builtin_nontemporal_store(o, ((f32x4*)orow) + 1);
    }
}

extern "C" void kernel_launch(void* const* d_in, const int* in_sizes, int n_in,
                              void* d_out, int out_size, void* d_ws, size_t ws_size,
                              hipStream_t stream) {
    const float* h    = (const float*)d_in[0];
    const int*   src  = (const int*)d_in[1];
    const int*   dst  = (const int*)d_in[2];
    const float* W    = (const float*)d_in[3];
    const float* attn = (const float*)d_in[4];
    const int N = in_sizes[0] / DD;
    const int E = in_sizes[1];
    float* out = (float*)d_out;

    // workspace layout
    unsigned short* z16 = (unsigned short*)d_ws;          // N*128 bf16 (12.8 MB)
    float* ll  = (float*)(z16 + (size_t)N * DD);          // N
    float* lr  = ll + N;                                  // N
    int* start = (int*)(lr + N);                          // N+1

    const int NB = (N + 127) / 128;          // gemm blocks
    const int SB = (N + 1 + 255) / 256;      // starts blocks

    k_gemm<<<NB + SB, 256, 0, stream>>>(h, W, attn, dst, E, N, NB, z16, ll, lr, start);
    k_out<<<(N + 3) / 4, 256, 0, stream>>>(z16, src, ll, lr, start, out, N);
}

// Round 10
// 51.755 us; speedup vs baseline: 1.5338x; 1.0731x over previous
//
#include <hip/hip_runtime.h>
#include <hip/hip_bf16.h>

#define DD 128
#define NEGS 0.01f

typedef float  f32x4 __attribute__((ext_vector_type(4)));
typedef __bf16 bf16x8 __attribute__((ext_vector_type(8)));
typedef unsigned short us8 __attribute__((ext_vector_type(8)));

__device__ __forceinline__ unsigned short f2bf(float f) {
    unsigned int u = __builtin_bit_cast(unsigned int, f);
    u += 0x7FFFu + ((u >> 16) & 1u);          // RNE (no NaN inputs here)
    return (unsigned short)(u >> 16);
}
__device__ __forceinline__ float sb2f(unsigned int u, int byte) {
    return (float)(int)(signed char)((u >> (byte * 8)) & 0xffu);
}

// ---------- fused GEMM + logits + row-quant + segment-starts ---------------
// Blocks [0,NB): GEMM, 256 thr = 4 waves x 32 rows = 128 rows/block.
// h/W staged in LDS as bf16 (slot-swizzled, ds_read_b128 ~2-way = free).
// Epilogue: ll/lr logits + per-row absmax -> z8 = int8(z*127/rowmax),
// lls[row] = {ll, rowmax/127}. Blocks [NB,NB+SB): start[]=lower_bound(dst,n).
__global__ __launch_bounds__(256)
void k_gemm(const float* __restrict__ h, const float* __restrict__ W,
            const float* __restrict__ attn, const int* __restrict__ dst,
            int E, int N, int NB,
            signed char* __restrict__ z8, float2* __restrict__ lls,
            float* __restrict__ lrv, int* __restrict__ start)
{
    if (blockIdx.x >= NB) {               // ---- segment starts part ----
        int n = (blockIdx.x - NB) * 256 + threadIdx.x;
        if (n > N) return;
        int lo = 0, hi = E;
        while (lo < hi) {
            int mid = (lo + hi) >> 1;
            if (dst[mid] < n) lo = mid + 1; else hi = mid;
        }
        start[n] = lo;
        return;
    }

    __shared__ unsigned short hs[128 * DD];   // 32 KB, swizzled bf16
    __shared__ unsigned short ws[DD * DD];    // 32 KB, swizzled bf16
    const int tid  = threadIdx.x;
    const int row0 = blockIdx.x * 128;

    {   // stage W (fp32 -> bf16, swizzled)
        const int r = tid >> 4, c = tid & 15;
#pragma unroll
        for (int p = 0; p < DD; p += 16) {
            const int rr = p + r;
            const float* pw = W + (size_t)rr * DD + c * 8;
            float4 a = *(const float4*)pw, b = *(const float4*)(pw + 4);
            us8 v = { f2bf(a.x), f2bf(a.y), f2bf(a.z), f2bf(a.w),
                      f2bf(b.x), f2bf(b.y), f2bf(b.z), f2bf(b.w) };
            *(us8*)(ws + rr * DD + ((c ^ (rr & 15)) * 8)) = v;
        }
    }
    {   // stage h rows [row0, row0+128) (clamped)
        const int r = tid >> 4, c = tid & 15;
#pragma unroll
        for (int p = 0; p < 128; p += 16) {
            const int rr = p + r;
            int gr = row0 + rr; if (gr > N - 1) gr = N - 1;
            const float* ph = h + (size_t)gr * DD + c * 8;
            float4 a = *(const float4*)ph, b = *(const float4*)(ph + 4);
            us8 v = { f2bf(a.x), f2bf(a.y), f2bf(a.z), f2bf(a.w),
                      f2bf(b.x), f2bf(b.y), f2bf(b.z), f2bf(b.w) };
            *(us8*)(hs + rr * DD + ((c ^ (rr & 15)) * 8)) = v;
        }
    }
    __syncthreads();

    const int w    = tid >> 6;
    const int lane = tid & 63;
    const int hl   = lane & 15;
    const int g    = lane >> 4;

    f32x4 acc[2][8];
#pragma unroll
    for (int rt = 0; rt < 2; ++rt)
#pragma unroll
        for (int jt = 0; jt < 8; ++jt) acc[rt][jt] = f32x4{0.f, 0.f, 0.f, 0.f};

#pragma unroll
    for (int kk = 0; kk < DD; kk += 32) {
        const int cb = (kk >> 3) + g;
        const int ra0 = w * 32 + hl;
        const int ra1 = ra0 + 16;
        bf16x8 a0 = *(const bf16x8*)(hs + ra0 * DD + ((cb ^ (ra0 & 15)) * 8));
        bf16x8 a1 = *(const bf16x8*)(hs + ra1 * DD + ((cb ^ (ra1 & 15)) * 8));
#pragma unroll
        for (int jt = 0; jt < 8; ++jt) {
            const int rb = jt * 16 + hl;
            bf16x8 b = *(const bf16x8*)(ws + rb * DD + ((cb ^ (rb & 15)) * 8));
            acc[0][jt] = __builtin_amdgcn_mfma_f32_16x16x32_bf16(a0, b, acc[0][jt], 0, 0, 0);
            acc[1][jt] = __builtin_amdgcn_mfma_f32_16x16x32_bf16(a1, b, acc[1][jt], 0, 0, 0);
        }
    }

    // epilogue: logits + row absmax + int8 quantize
    float aLc[8], aRc[8];
#pragma unroll
    for (int jt = 0; jt < 8; ++jt) {
        aLc[jt] = attn[jt * 16 + hl];
        aRc[jt] = attn[DD + jt * 16 + hl];
    }
#pragma unroll
    for (int rt = 0; rt < 2; ++rt) {
#pragma unroll
        for (int reg = 0; reg < 4; ++reg) {
            const int row = row0 + w * 32 + rt * 16 + g * 4 + reg;
            float pl = 0.f, pr = 0.f, am = 0.f;
#pragma unroll
            for (int jt = 0; jt < 8; ++jt) {
                float v = acc[rt][jt][reg];
                pl = fmaf(v, aLc[jt], pl);
                pr = fmaf(v, aRc[jt], pr);
                am = fmaxf(am, fabsf(v));
            }
#pragma unroll
            for (int o = 8; o >= 1; o >>= 1) {   // reduce across 16 cols
                pl += __shfl_xor(pl, o);
                pr += __shfl_xor(pr, o);
                am = fmaxf(am, __shfl_xor(am, o));
            }
            if (row < N) {
                const float inv_s = (am > 0.f) ? 127.f / am : 0.f;
                if (hl == 0) {
                    lls[row] = make_float2(pl, am * (1.f / 127.f));
                    lrv[row] = pr;
                }
                signed char* zr = z8 + (size_t)row * DD;
#pragma unroll
                for (int jt = 0; jt < 8; ++jt)
                    zr[jt * 16 + hl] =
                        (signed char)__float2int_rn(acc[rt][jt][reg] * inv_s);
            }
        }
    }
}

// ---------------- fused output: int8 z gather (2 lines/row) ---------------
// wave = node; 4 quarter-waves, 2 edges each per iter (8 edges/iter).
// lls[src] = {ll, s}: one 8B load gives logit + dequant scale (1 line, same
// as the old ll gather). Denominator uses raw w; numerator uses w*s_src.
// No max-subtraction (logits O(10), exp fp32-safe, softmax shift-invariant).
__global__ __launch_bounds__(256)
void k_out(const signed char* __restrict__ z8, const int* __restrict__ src,
           const float2* __restrict__ lls, const float* __restrict__ lrv,
           const int* __restrict__ start, float* __restrict__ out, int N)
{
    int wid  = (blockIdx.x * 256 + threadIdx.x) >> 6;
    int lane = threadIdx.x & 63;
    if (wid >= N) return;
    const int s0 = start[wid], s1 = start[wid + 1];
    const int q = lane >> 4;      // quarter 0..3
    const int c = lane & 15;      // byte block: cols 8c .. 8c+7
    const float lrn = lrv[wid];

    float acc[8];
#pragma unroll
    for (int k = 0; k < 8; ++k) acc[k] = 0.f;
    float ssum = 0.f;
    const int last = s1 - 1;

    for (int base = s0; base < s1; base += 8) {
        int t0 = base + q;
        int t1 = t0 + 4;
        int tc0 = (t0 <= last) ? t0 : last;
        int tc1 = (t1 <= last) ? t1 : last;
        int sj0 = __builtin_nontemporal_load(src + tc0);
        int sj1 = __builtin_nontemporal_load(src + tc1);
        float2 p0 = lls[sj0];
        float2 p1 = lls[sj1];
        float v0 = p0.x + lrn;  v0 = (v0 >= 0.f) ? v0 : NEGS * v0;
        float v1 = p1.x + lrn;  v1 = (v1 >= 0.f) ? v1 : NEGS * v1;
        float w0 = __expf(v0); if (t0 > last) w0 = 0.f;
        float w1 = __expf(v1); if (t1 > last) w1 = 0.f;
        uint2 z0 = *(const uint2*)(z8 + (size_t)sj0 * DD + c * 8);
        uint2 z1 = *(const uint2*)(z8 + (size_t)sj1 * DD + c * 8);
        ssum += w0 + w1;                 // raw weights for the denominator
        float u0 = w0 * p0.y;            // scaled weights for the numerator
        float u1 = w1 * p1.y;
        acc[0] = fmaf(u0, sb2f(z0.x, 0), fmaf(u1, sb2f(z1.x, 0), acc[0]));
        acc[1] = fmaf(u0, sb2f(z0.x, 1), fmaf(u1, sb2f(z1.x, 1), acc[1]));
        acc[2] = fmaf(u0, sb2f(z0.x, 2), fmaf(u1, sb2f(z1.x, 2), acc[2]));
        acc[3] = fmaf(u0, sb2f(z0.x, 3), fmaf(u1, sb2f(z1.x, 3), acc[3]));
        acc[4] = fmaf(u0, sb2f(z0.y, 0), fmaf(u1, sb2f(z1.y, 0), acc[4]));
        acc[5] = fmaf(u0, sb2f(z0.y, 1), fmaf(u1, sb2f(z1.y, 1), acc[5]));
        acc[6] = fmaf(u0, sb2f(z0.y, 2), fmaf(u1, sb2f(z1.y, 2), acc[6]));
        acc[7] = fmaf(u0, sb2f(z0.y, 3), fmaf(u1, sb2f(z1.y, 3), acc[7]));
    }
    // combine the 4 quarters (lanes {l, l^16, l^32, l^48} share a col block)
#pragma unroll
    for (int k = 0; k < 8; ++k) {
        acc[k] += __shfl_xor(acc[k], 16);
        acc[k] += __shfl_xor(acc[k], 32);
    }
    ssum += __shfl_xor(ssum, 16);
    ssum += __shfl_xor(ssum, 32);
    float inv = (s1 > s0) ? 1.0f / ssum : 0.f;   // empty segment -> zeros

    float* orow = out + (size_t)wid * DD + c * 8;
    if (q == 0) {
        f32x4 o = {acc[0]*inv, acc[1]*inv, acc[2]*inv, acc[3]*inv};
        __builtin_nontemporal_store(o, (f32x4*)orow);
    } else if (q == 1) {
        f32x4 o = {acc[4]*inv, acc[5]*inv, acc[6]*inv, acc[7]*inv};
        __builtin_nontemporal_store(o, ((f32x4*)orow) + 1);
    }
}

extern "C" void kernel_launch(void* const* d_in, const int* in_sizes, int n_in,
                              void* d_out, int out_size, void* d_ws, size_t ws_size,
                              hipStream_t stream) {
    const float* h    = (const float*)d_in[0];
    const int*   src  = (const int*)d_in[1];
    const int*   dst  = (const int*)d_in[2];
    const float* W    = (const float*)d_in[3];
    const float* attn = (const float*)d_in[4];
    const int N = in_sizes[0] / DD;
    const int E = in_sizes[1];
    float* out = (float*)d_out;

    // workspace layout (z8 6.4 MB, lls 400 KB, lrv 200 KB, start)
    signed char* z8 = (signed char*)d_ws;               // N*128 int8
    float2* lls = (float2*)(z8 + (size_t)N * DD);       // N float2 {ll, s}
    float* lrv  = (float*)(lls + N);                    // N
    int* start  = (int*)(lrv + N);                      // N+1

    const int NB = (N + 127) / 128;          // gemm blocks
    const int SB = (N + 1 + 255) / 256;      // starts blocks

    k_gemm<<<NB + SB, 256, 0, stream>>>(h, W, attn, dst, E, N, NB, z8, lls, lrv, start);
    k_out<<<(N + 3) / 4, 256, 0, stream>>>(z8, src, lls, lrv, start, out, N);
}